// Round 1
// baseline (331.784 us; speedup 1.0000x reference)
//
#include <hip/hip_runtime.h>

// Problem constants
#define B_    4
#define S_    2048
#define HID_  1024
#define NO_   1024     // NH*HD
#define EPS_  1e-6f
#define M1_   (B_ * S_)   // 8192

typedef __attribute__((ext_vector_type(8))) short  short8;
typedef __attribute__((ext_vector_type(4))) float  f32x4;

__device__ inline unsigned short f2bf(float f) {
  union { float f; unsigned int u; } v; v.f = f;
  unsigned int r = v.u + 0x7FFFu + ((v.u >> 16) & 1u);  // RNE
  return (unsigned short)(r >> 16);
}

// ---------------------------------------------------------------------------
// Kernel 0: WvT[n][k] = bf16(Wv[k][n]).  32x32 LDS tiles, both sides coalesced.
// ---------------------------------------------------------------------------
__global__ void k_twv(const float* __restrict__ Wv, unsigned short* __restrict__ WvT) {
  __shared__ float tile[32][33];
  int k0 = blockIdx.x * 32;
  int n0 = blockIdx.y * 32;
  int tx = threadIdx.x, ty = threadIdx.y;
  for (int i = ty; i < 32; i += 8)
    tile[i][tx] = Wv[(size_t)(k0 + i) * NO_ + n0 + tx];
  __syncthreads();
  for (int i = ty; i < 32; i += 8)
    WvT[(size_t)(n0 + i) * HID_ + k0 + tx] = f2bf(tile[tx][i]);
}

// ---------------------------------------------------------------------------
// Kernel 1: Vt[b][n][s] = bf16( sum_k WvT[n][k]*H[b,s,k] + bv[n] )
// D[n][m] = WvT(bf16) @ H^T, m = b*S+s.  128x128 tile, BK=32, 4 waves.
// ---------------------------------------------------------------------------
__global__ __launch_bounds__(256) void k_vt(
    const unsigned short* __restrict__ WvT, const float* __restrict__ H,
    const float* __restrict__ bv, unsigned short* __restrict__ Vt) {
  __shared__ __align__(16) unsigned short lds_a[128 * 40];  // [n_local][k], pad 40
  __shared__ __align__(16) unsigned short lds_b[128 * 40];  // [m_local][k]
  int m0 = blockIdx.x * 128;
  int n0 = blockIdx.y * 128;
  int tid = threadIdx.x;
  int wave = tid >> 6, lane = tid & 63;
  int wr = wave >> 1, wc = wave & 1;
  int lq = lane >> 4, lm = lane & 15;

  f32x4 acc[4][4];
  for (int i = 0; i < 4; i++) for (int j = 0; j < 4; j++) acc[i][j] = (f32x4)0.0f;

  for (int k0 = 0; k0 < HID_; k0 += 32) {
    // stage A: WvT tile (bf16 direct copy), 64 rows/iter x 2
    {
      int r = tid >> 2;
      int c = (tid & 3) * 8;
      for (int i = 0; i < 2; i++) {
        *(uint4*)&lds_a[(r + i * 64) * 40 + c] =
            *(const uint4*)(WvT + (size_t)(n0 + r + i * 64) * HID_ + k0 + c);
      }
    }
    // stage B: H tile fp32 -> bf16, 32 rows/iter x 4
    {
      int r = tid >> 3;
      int c = (tid & 7) * 4;
      for (int i = 0; i < 4; i++) {
        float4 v = *(const float4*)(H + (size_t)(m0 + r + i * 32) * HID_ + k0 + c);
        unsigned long long p = (unsigned long long)f2bf(v.x)
                             | ((unsigned long long)f2bf(v.y) << 16)
                             | ((unsigned long long)f2bf(v.z) << 32)
                             | ((unsigned long long)f2bf(v.w) << 48);
        *(unsigned long long*)&lds_b[(r + i * 32) * 40 + c] = p;
      }
    }
    __syncthreads();
    short8 af[4], bfr[4];
    for (int mi = 0; mi < 4; mi++)
      af[mi] = *(const short8*)&lds_a[(wr * 64 + mi * 16 + lm) * 40 + lq * 8];
    for (int ni = 0; ni < 4; ni++)
      bfr[ni] = *(const short8*)&lds_b[(wc * 64 + ni * 16 + lm) * 40 + lq * 8];
    for (int mi = 0; mi < 4; mi++)
      for (int ni = 0; ni < 4; ni++)
        acc[mi][ni] = __builtin_amdgcn_mfma_f32_16x16x32_bf16(af[mi], bfr[ni], acc[mi][ni], 0, 0, 0);
    __syncthreads();
  }
  // epilogue: row n gets +bv[n]; store bf16 to Vt[b][n][s]
  for (int mi = 0; mi < 4; mi++) {
    for (int r = 0; r < 4; r++) {
      int n = n0 + wr * 64 + mi * 16 + lq * 4 + r;
      float bias = bv[n];
      for (int ni = 0; ni < 4; ni++) {
        int m = m0 + wc * 64 + ni * 16 + lm;
        int b = m >> 11;       // m / 2048
        int s = m & 2047;
        Vt[((size_t)b * NO_ + n) * S_ + s] = f2bf(acc[mi][ni][r] + bias);
      }
    }
  }
}

// ---------------------------------------------------------------------------
// Kernel 2: inv[b*S+q] = 1/(eps + sum_{k<=q} A[b,q,k]).  One wave per row.
// ---------------------------------------------------------------------------
__global__ __launch_bounds__(256) void k_rowsum(const float* __restrict__ A,
                                                float* __restrict__ inv) {
  int row  = blockIdx.x * 4 + (threadIdx.x >> 6);
  int lane = threadIdx.x & 63;
  int b = row >> 11;
  int q = row & 2047;
  const float* rp = A + ((size_t)b * S_ + q) * S_;
  float s = 0.f;
  for (int k = lane * 4; k <= q; k += 256) {
    float4 v = *(const float4*)(rp + k);   // k+3 <= 2047 always: in-bounds
    s += v.x;
    if (k + 1 <= q) s += v.y;
    if (k + 2 <= q) s += v.z;
    if (k + 3 <= q) s += v.w;
  }
  for (int off = 32; off > 0; off >>= 1) s += __shfl_xor(s, off, 64);
  if (lane == 0) inv[row] = 1.0f / (EPS_ + s);
}

// ---------------------------------------------------------------------------
// Kernel 3: out[b,q,n] = inv[b,q] * sum_{k<=q} A[b,q,k] * V[b,k,n]
// A-operand: attn tile fp32->bf16 with causal mask; B-operand: Vt rows (bf16).
// Causal K-loop truncation: tiles 0 .. q0/32+3.
// ---------------------------------------------------------------------------
__global__ __launch_bounds__(256) void k_attn(
    const float* __restrict__ A, const unsigned short* __restrict__ Vt,
    const float* __restrict__ inv, float* __restrict__ out) {
  __shared__ __align__(16) unsigned short lds_a[128 * 40];  // [q_local][k]
  __shared__ __align__(16) unsigned short lds_b[128 * 40];  // [n_local][k]
  int n0 = blockIdx.x * 128;
  int q0 = ((int)gridDim.y - 1 - (int)blockIdx.y) * 128;  // heavy tiles first
  int b  = blockIdx.z;
  int tid = threadIdx.x;
  int wave = tid >> 6, lane = tid & 63;
  int wr = wave >> 1, wc = wave & 1;
  int lq = lane >> 4, lm = lane & 15;
  const float*          Ab = A  + (size_t)b * S_ * S_;
  const unsigned short* Vb = Vt + (size_t)b * NO_ * S_;

  f32x4 acc[4][4];
  for (int i = 0; i < 4; i++) for (int j = 0; j < 4; j++) acc[i][j] = (f32x4)0.0f;

  const int kend = q0 + 128;   // exclusive; covers all k <= q for this q-tile
  for (int k0 = 0; k0 < kend; k0 += 32) {
    const bool mask = (k0 + 31 > q0);
    // stage A: fp32 -> bf16 with causal mask, 32 rows/iter x 4
    {
      int r = tid >> 3;
      int c = (tid & 7) * 4;
      for (int i = 0; i < 4; i++) {
        int q = q0 + r + i * 32;
        float4 v = *(const float4*)(Ab + (size_t)q * S_ + k0 + c);
        if (mask) {
          if (k0 + c + 0 > q) v.x = 0.f;
          if (k0 + c + 1 > q) v.y = 0.f;
          if (k0 + c + 2 > q) v.z = 0.f;
          if (k0 + c + 3 > q) v.w = 0.f;
        }
        unsigned long long p = (unsigned long long)f2bf(v.x)
                             | ((unsigned long long)f2bf(v.y) << 16)
                             | ((unsigned long long)f2bf(v.z) << 32)
                             | ((unsigned long long)f2bf(v.w) << 48);
        *(unsigned long long*)&lds_a[(r + i * 32) * 40 + c] = p;
      }
    }
    // stage B: Vt rows (bf16 direct), 64 rows/iter x 2
    {
      int r = tid >> 2;
      int c = (tid & 3) * 8;
      for (int i = 0; i < 2; i++) {
        *(uint4*)&lds_b[(r + i * 64) * 40 + c] =
            *(const uint4*)(Vb + (size_t)(n0 + r + i * 64) * S_ + k0 + c);
      }
    }
    __syncthreads();
    short8 af[4], bfr[4];
    for (int mi = 0; mi < 4; mi++)
      af[mi] = *(const short8*)&lds_a[(wr * 64 + mi * 16 + lm) * 40 + lq * 8];
    for (int ni = 0; ni < 4; ni++)
      bfr[ni] = *(const short8*)&lds_b[(wc * 64 + ni * 16 + lm) * 40 + lq * 8];
    for (int mi = 0; mi < 4; mi++)
      for (int ni = 0; ni < 4; ni++)
        acc[mi][ni] = __builtin_amdgcn_mfma_f32_16x16x32_bf16(af[mi], bfr[ni], acc[mi][ni], 0, 0, 0);
    __syncthreads();
  }
  // epilogue: scale row by inv[b,q], fp32 store (coalesced across lm)
  for (int mi = 0; mi < 4; mi++) {
    for (int r = 0; r < 4; r++) {
      int q = q0 + wr * 64 + mi * 16 + lq * 4 + r;
      float sc = inv[b * S_ + q];
      for (int ni = 0; ni < 4; ni++) {
        int n = n0 + wc * 64 + ni * 16 + lm;
        out[((size_t)b * S_ + q) * NO_ + n] = acc[mi][ni][r] * sc;
      }
    }
  }
}

// ---------------------------------------------------------------------------
extern "C" void kernel_launch(void* const* d_in, const int* in_sizes, int n_in,
                              void* d_out, int out_size, void* d_ws, size_t ws_size,
                              hipStream_t stream) {
  const float* H  = (const float*)d_in[0];   // hidden_states [B,S,HID]
  const float* A  = (const float*)d_in[1];   // assoc_hc_attn [B,S,S]
  // d_in[2] = broad_hc_attn (unused: broad_heads == 0)
  const float* Wv = (const float*)d_in[3];   // [HID, NO]
  const float* bv = (const float*)d_in[4];   // [NO]
  float* out = (float*)d_out;

  char* ws = (char*)d_ws;
  unsigned short* WvT = (unsigned short*)ws;                                   // 2 MB
  unsigned short* Vt  = (unsigned short*)(ws + (size_t)HID_ * NO_ * 2);        // 16 MB
  float*          inv = (float*)(ws + (size_t)HID_ * NO_ * 2
                                    + (size_t)B_ * NO_ * S_ * 2);              // 32 KB

  k_twv   <<<dim3(HID_ / 32, NO_ / 32), dim3(32, 8), 0, stream>>>(Wv, WvT);
  k_vt    <<<dim3(M1_ / 128, NO_ / 128), 256, 0, stream>>>(WvT, H, bv, Vt);
  k_rowsum<<<M1_ / 4, 256, 0, stream>>>(A, inv);
  k_attn  <<<dim3(NO_ / 128, S_ / 128, B_), 256, 0, stream>>>(A, Vt, inv, out);
}

// Round 2
// 251.883 us; speedup vs baseline: 1.3172x; 1.3172x over previous
//
#include <hip/hip_runtime.h>

// Problem constants
#define B_    4
#define S_    2048
#define HID_  1024
#define NO_   1024     // NH*HD
#define EPS_  1e-6f
#define M1_   (B_ * S_)   // 8192

typedef __attribute__((ext_vector_type(8))) short  short8;
typedef __attribute__((ext_vector_type(4))) float  f32x4;
typedef unsigned short ushort_t;

__device__ __forceinline__ unsigned short f2bf(float f) {
  union { float f; unsigned int u; } v; v.f = f;
  unsigned int r = v.u + 0x7FFFu + ((v.u >> 16) & 1u);  // RNE
  return (unsigned short)(r >> 16);
}
__device__ __forceinline__ unsigned pack2(float a, float b) {
  return (unsigned)f2bf(a) | ((unsigned)f2bf(b) << 16);
}

// async global->LDS, 16B per lane. LDS dest must be wave-uniform base (+lane*16 by HW).
typedef __attribute__((address_space(1))) const void GASV;
typedef __attribute__((address_space(3))) void LASV;
__device__ __forceinline__ void gld16(const void* g, void* l) {
  __builtin_amdgcn_global_load_lds((GASV*)g, (LASV*)l, 16, 0, 0);
}

// ---------------------------------------------------------------------------
// Prep 0: WvT[n][k] = bf16(Wv[k][n])
// ---------------------------------------------------------------------------
__global__ void k_twv(const float* __restrict__ Wv, ushort_t* __restrict__ WvT) {
  __shared__ float tile[32][33];
  int k0 = blockIdx.x * 32;
  int n0 = blockIdx.y * 32;
  int tx = threadIdx.x, ty = threadIdx.y;
  for (int i = ty; i < 32; i += 8)
    tile[i][tx] = Wv[(size_t)(k0 + i) * NO_ + n0 + tx];
  __syncthreads();
  for (int i = ty; i < 32; i += 8)
    WvT[(size_t)(n0 + i) * HID_ + k0 + tx] = f2bf(tile[tx][i]);
}

// ---------------------------------------------------------------------------
// Prep 1: Hb = bf16(H), elementwise. 8192 blocks x 256 thr x 4 elems.
// ---------------------------------------------------------------------------
__global__ __launch_bounds__(256) void k_cvtH(const float* __restrict__ H,
                                              ushort_t* __restrict__ Hb) {
  size_t i = ((size_t)blockIdx.x * 256 + threadIdx.x) * 4;
  float4 v = *(const float4*)(H + i);
  uint2 p; p.x = pack2(v.x, v.y); p.y = pack2(v.z, v.w);
  *(uint2*)(Hb + i) = p;
}

// ---------------------------------------------------------------------------
// Prep 2: per row q: inv = 1/(eps + sum_{k<=q} A); Ab[row][k] = bf16(A*inv) for
// k<=q else 0, written up to wend = next 128 boundary (all any GEMM block reads).
// One wave per row.
// ---------------------------------------------------------------------------
__global__ __launch_bounds__(256) void k_prepA(const float* __restrict__ A,
                                               ushort_t* __restrict__ Ab) {
  int row  = blockIdx.x * 4 + (threadIdx.x >> 6);   // row = b*S + q
  int lane = threadIdx.x & 63;
  int q = row & 2047;
  const float* rp = A + (size_t)row * S_;
  float s = 0.f;
  for (int k = lane * 4; k <= q; k += 256) {
    float4 v = *(const float4*)(rp + k);
    s += v.x;
    if (k + 1 <= q) s += v.y;
    if (k + 2 <= q) s += v.z;
    if (k + 3 <= q) s += v.w;
  }
  for (int off = 1; off < 64; off <<= 1) s += __shfl_xor(s, off, 64);
  float inv = 1.0f / (EPS_ + s);
  int wend = ((q >> 7) + 1) << 7;
  ushort_t* op = Ab + (size_t)row * S_;
  for (int k = lane * 4; k < wend; k += 256) {
    float4 v = *(const float4*)(rp + k);
    float x0 = (k + 0 <= q) ? v.x * inv : 0.f;
    float x1 = (k + 1 <= q) ? v.y * inv : 0.f;
    float x2 = (k + 2 <= q) ? v.z * inv : 0.f;
    float x3 = (k + 3 <= q) ? v.w * inv : 0.f;
    uint2 p; p.x = pack2(x0, x1); p.y = pack2(x2, x3);
    *(uint2*)(op + k) = p;
  }
}

// ---------------------------------------------------------------------------
// GEMM 1: Vt[b][n][s] = bf16( sum_k WvT[n][k]*Hb[m][k] + bv[n] ), m=b*S+s.
// 128x128 tile, BK=32, 4 waves, global_load_lds staging, XOR-swizzled LDS.
// ---------------------------------------------------------------------------
__global__ __launch_bounds__(256) void k_vt(
    const ushort_t* __restrict__ WvT, const ushort_t* __restrict__ Hb,
    const float* __restrict__ bv, ushort_t* __restrict__ Vt) {
  __shared__ __align__(16) ushort_t lds_a[128 * 32];  // 8 KB, rows = n
  __shared__ __align__(16) ushort_t lds_b[128 * 32];  // 8 KB, rows = m
  int m0 = blockIdx.x * 128;
  int n0 = blockIdx.y * 128;
  int tid = threadIdx.x;
  int wave = tid >> 6, lane = tid & 63;
  int wr = wave >> 1, wc = wave & 1;
  int lq = lane >> 4, lm = lane & 15;

  // staging: lane covers (row sr (+64 for round 1), 16B chunk sc), swizzled
  int sr = wave * 16 + (lane >> 2);
  int sc = (lane & 3) ^ ((sr >> 1) & 3);
  const ushort_t* gA0 = WvT + (size_t)(n0 + sr) * HID_ + sc * 8;
  const ushort_t* gA1 = gA0 + (size_t)64 * HID_;
  const ushort_t* gB0 = Hb + (size_t)(m0 + sr) * HID_ + sc * 8;
  const ushort_t* gB1 = gB0 + (size_t)64 * HID_;
  char* la = (char*)lds_a;
  char* lb = (char*)lds_b;
  unsigned wslot = wave * 1024;
  int swz = (lm >> 1) & 3;

  f32x4 acc[4][4];
  for (int i = 0; i < 4; i++) for (int j = 0; j < 4; j++) acc[i][j] = (f32x4)0.0f;

  for (int it = 0; it < HID_ / 32; it++) {
    gld16(gA0, la + wslot);        gld16(gA1, la + 4096 + wslot);
    gld16(gB0, lb + wslot);        gld16(gB1, lb + 4096 + wslot);
    gA0 += 32; gA1 += 32; gB0 += 32; gB1 += 32;
    __syncthreads();
    short8 af[4], bfr[4];
#pragma unroll
    for (int mi = 0; mi < 4; mi++)
      af[mi] = *(const short8*)(la + (wr * 64 + mi * 16 + lm) * 64 + ((lq ^ swz) << 4));
#pragma unroll
    for (int ni = 0; ni < 4; ni++)
      bfr[ni] = *(const short8*)(lb + (wc * 64 + ni * 16 + lm) * 64 + ((lq ^ swz) << 4));
#pragma unroll
    for (int mi = 0; mi < 4; mi++)
#pragma unroll
      for (int ni = 0; ni < 4; ni++)
        acc[mi][ni] = __builtin_amdgcn_mfma_f32_16x16x32_bf16(af[mi], bfr[ni], acc[mi][ni], 0, 0, 0);
    __syncthreads();
  }
  for (int mi = 0; mi < 4; mi++) {
    for (int r = 0; r < 4; r++) {
      int n = n0 + wr * 64 + mi * 16 + lq * 4 + r;
      float bias = bv[n];
      for (int ni = 0; ni < 4; ni++) {
        int m = m0 + wc * 64 + ni * 16 + lm;
        int b = m >> 11;
        int s = m & 2047;
        Vt[((size_t)b * NO_ + n) * S_ + s] = f2bf(acc[mi][ni][r] + bias);
      }
    }
  }
}

// ---------------------------------------------------------------------------
// GEMM 2: out[b,q,n] = sum_k Ab[b,q,k] * Vt[b,n,k]   (inv pre-applied in Ab)
// grid (32, 16): x -> (n-tile, b), y -> q-tile (heavy first).
// ---------------------------------------------------------------------------
__global__ __launch_bounds__(256) void k_attn(
    const ushort_t* __restrict__ Ab, const ushort_t* __restrict__ Vt,
    float* __restrict__ out) {
  __shared__ __align__(16) ushort_t lds_a[128 * 32];  // rows = q
  __shared__ __align__(16) ushort_t lds_b[128 * 32];  // rows = n
  int n0 = (blockIdx.x & 7) * 128;
  int b  = blockIdx.x >> 3;
  int q0 = (15 - (int)blockIdx.y) * 128;  // heavy tiles dispatched first
  int tid = threadIdx.x;
  int wave = tid >> 6, lane = tid & 63;
  int wr = wave >> 1, wc = wave & 1;
  int lq = lane >> 4, lm = lane & 15;

  int sr = wave * 16 + (lane >> 2);
  int sc = (lane & 3) ^ ((sr >> 1) & 3);
  const ushort_t* gA0 = Ab + ((size_t)(b * S_ + q0 + sr)) * S_ + sc * 8;
  const ushort_t* gA1 = gA0 + (size_t)64 * S_;
  const ushort_t* gB0 = Vt + ((size_t)(b * NO_ + n0 + sr)) * S_ + sc * 8;
  const ushort_t* gB1 = gB0 + (size_t)64 * S_;
  char* la = (char*)lds_a;
  char* lb = (char*)lds_b;
  unsigned wslot = wave * 1024;
  int swz = (lm >> 1) & 3;

  f32x4 acc[4][4];
  for (int i = 0; i < 4; i++) for (int j = 0; j < 4; j++) acc[i][j] = (f32x4)0.0f;

  const int iters = (q0 >> 5) + 4;   // kend = q0+128, BK=32
  for (int it = 0; it < iters; it++) {
    gld16(gA0, la + wslot);        gld16(gA1, la + 4096 + wslot);
    gld16(gB0, lb + wslot);        gld16(gB1, lb + 4096 + wslot);
    gA0 += 32; gA1 += 32; gB0 += 32; gB1 += 32;
    __syncthreads();
    short8 af[4], bfr[4];
#pragma unroll
    for (int mi = 0; mi < 4; mi++)
      af[mi] = *(const short8*)(la + (wr * 64 + mi * 16 + lm) * 64 + ((lq ^ swz) << 4));
#pragma unroll
    for (int ni = 0; ni < 4; ni++)
      bfr[ni] = *(const short8*)(lb + (wc * 64 + ni * 16 + lm) * 64 + ((lq ^ swz) << 4));
#pragma unroll
    for (int mi = 0; mi < 4; mi++)
#pragma unroll
      for (int ni = 0; ni < 4; ni++)
        acc[mi][ni] = __builtin_amdgcn_mfma_f32_16x16x32_bf16(af[mi], bfr[ni], acc[mi][ni], 0, 0, 0);
    __syncthreads();
  }
  for (int mi = 0; mi < 4; mi++) {
    for (int r = 0; r < 4; r++) {
      int q = q0 + wr * 64 + mi * 16 + lq * 4 + r;
      for (int ni = 0; ni < 4; ni++) {
        int n = n0 + wc * 64 + ni * 16 + lm;
        out[((size_t)b * S_ + q) * NO_ + n] = acc[mi][ni][r];
      }
    }
  }
}

// ---------------------------------------------------------------------------
extern "C" void kernel_launch(void* const* d_in, const int* in_sizes, int n_in,
                              void* d_out, int out_size, void* d_ws, size_t ws_size,
                              hipStream_t stream) {
  const float* H  = (const float*)d_in[0];   // [B,S,HID]
  const float* A  = (const float*)d_in[1];   // [B,S,S]
  const float* Wv = (const float*)d_in[3];   // [HID, NO]
  const float* bv = (const float*)d_in[4];   // [NO]
  float* out = (float*)d_out;

  char* ws = (char*)d_ws;
  ushort_t* WvT = (ushort_t*)ws;                                  //  2.0 MB
  ushort_t* Hb  = (ushort_t*)(ws + 2097152);                      // 16.8 MB
  ushort_t* Vt  = (ushort_t*)(ws + 2097152 + 16777216);           // 16.8 MB
  ushort_t* Abf = (ushort_t*)(ws + 2097152 + 2 * 16777216);       // 33.6 MB

  k_twv  <<<dim3(HID_ / 32, NO_ / 32), dim3(32, 8), 0, stream>>>(Wv, WvT);
  k_cvtH <<<(M1_ * HID_) / (256 * 4), 256, 0, stream>>>(H, Hb);
  k_prepA<<<M1_ / 4, 256, 0, stream>>>(A, Abf);
  k_vt   <<<dim3(M1_ / 128, NO_ / 128), 256, 0, stream>>>(WvT, Hb, bv, Vt);
  k_attn <<<dim3(32, 16), 256, 0, stream>>>(Abf, Vt, out);
}

// Round 3
// 245.056 us; speedup vs baseline: 1.3539x; 1.0279x over previous
//
#include <hip/hip_runtime.h>

// Problem constants
#define B_    4
#define S_    2048
#define HID_  1024
#define NO_   1024     // NH*HD
#define EPS_  1e-6f
#define M1_   (B_ * S_)   // 8192

typedef __attribute__((ext_vector_type(8))) short  short8;
typedef __attribute__((ext_vector_type(4))) float  f32x4;
typedef unsigned short ushort_t;

__device__ __forceinline__ unsigned short f2bf(float f) {
  union { float f; unsigned int u; } v; v.f = f;
  unsigned int r = v.u + 0x7FFFu + ((v.u >> 16) & 1u);  // RNE
  return (unsigned short)(r >> 16);
}
__device__ __forceinline__ unsigned pack2(float a, float b) {
  return (unsigned)f2bf(a) | ((unsigned)f2bf(b) << 16);
}

// async global->LDS, 16B per lane, dest = wave-uniform base + lane*16
typedef __attribute__((address_space(1))) const void GASV;
typedef __attribute__((address_space(3))) void LASV;
__device__ __forceinline__ void gld16(const void* g, void* l) {
  __builtin_amdgcn_global_load_lds((GASV*)g, (LASV*)l, 16, 0, 0);
}

// ---------------------------------------------------------------------------
// Prep 0: WvT[n][k] = bf16(Wv[k][n])
// ---------------------------------------------------------------------------
__global__ void k_twv(const float* __restrict__ Wv, ushort_t* __restrict__ WvT) {
  __shared__ float tile[32][33];
  int k0 = blockIdx.x * 32;
  int n0 = blockIdx.y * 32;
  int tx = threadIdx.x, ty = threadIdx.y;
  for (int i = ty; i < 32; i += 8)
    tile[i][tx] = Wv[(size_t)(k0 + i) * NO_ + n0 + tx];
  __syncthreads();
  for (int i = ty; i < 32; i += 8)
    WvT[(size_t)(n0 + i) * HID_ + k0 + tx] = f2bf(tile[tx][i]);
}

// ---------------------------------------------------------------------------
// Prep 1: Hb = bf16(H), elementwise
// ---------------------------------------------------------------------------
__global__ __launch_bounds__(256) void k_cvtH(const float* __restrict__ H,
                                              ushort_t* __restrict__ Hb) {
  size_t i = ((size_t)blockIdx.x * 256 + threadIdx.x) * 4;
  float4 v = *(const float4*)(H + i);
  uint2 p; p.x = pack2(v.x, v.y); p.y = pack2(v.z, v.w);
  *(uint2*)(Hb + i) = p;
}

// ---------------------------------------------------------------------------
// Prep 2 (single-pass): row in registers; inv = 1/(eps+causal rowsum);
// Ab[row][k] = bf16(A*inv) masked, written for k < wend = next 128 boundary.
// One wave per row; 32 floats/lane in VGPRs.
// ---------------------------------------------------------------------------
__global__ __launch_bounds__(256) void k_prepA(const float* __restrict__ A,
                                               ushort_t* __restrict__ Ab) {
  int row  = blockIdx.x * 4 + (threadIdx.x >> 6);   // row = b*S + q
  int lane = threadIdx.x & 63;
  int q = row & 2047;
  int wend = ((q >> 7) + 1) << 7;
  const float* rp = A + (size_t)row * S_;
  float4 v[8];
  float s = 0.f;
#pragma unroll
  for (int i = 0; i < 8; i++) {
    int k = i * 256 + lane * 4;
    if (k < wend) {
      float4 t = *(const float4*)(rp + k);
      t.x = (k + 0 <= q) ? t.x : 0.f;
      t.y = (k + 1 <= q) ? t.y : 0.f;
      t.z = (k + 2 <= q) ? t.z : 0.f;
      t.w = (k + 3 <= q) ? t.w : 0.f;
      v[i] = t;
      s += t.x + t.y + t.z + t.w;
    }
  }
  for (int off = 1; off < 64; off <<= 1) s += __shfl_xor(s, off, 64);
  float inv = 1.0f / (EPS_ + s);
  ushort_t* op = Ab + (size_t)row * S_;
#pragma unroll
  for (int i = 0; i < 8; i++) {
    int k = i * 256 + lane * 4;
    if (k < wend) {
      uint2 p;
      p.x = pack2(v[i].x * inv, v[i].y * inv);
      p.y = pack2(v[i].z * inv, v[i].w * inv);
      *(uint2*)(op + k) = p;
    }
  }
}

// ---------------------------------------------------------------------------
// GEMM 1: Vt[b][n][s] = bf16( sum_k WvT[n][k]*Hb[m][k] + bv[n] ), m=b*S+s.
// Tile n=64 x m=128, 2 waves (each 64x64), BK=32, grid 64x16 = 1024... (m x n)
// ---------------------------------------------------------------------------
__global__ __launch_bounds__(128) void k_vt(
    const ushort_t* __restrict__ WvT, const ushort_t* __restrict__ Hb,
    const float* __restrict__ bv, ushort_t* __restrict__ Vt) {
  __shared__ __align__(16) ushort_t lds_a[64 * 32];   // 4 KB, n-rows
  __shared__ __align__(16) ushort_t lds_b[128 * 32];  // 8 KB, m-rows
  int m0 = blockIdx.x * 128;
  int n0 = blockIdx.y * 64;
  int tid = threadIdx.x;
  int wave = tid >> 6, lane = tid & 63;
  int lq = lane >> 4, lm = lane & 15;

  int rr = lane >> 2;                       // 0..15 row within a 16-row call
  int sc = (lane & 3) ^ ((rr >> 1) & 3);    // swizzled 16B chunk
  const ushort_t* gA = WvT + (size_t)(n0 + wave * 32 + rr) * HID_ + sc * 8;
  const ushort_t* gB = Hb  + (size_t)(m0 + wave * 64 + rr) * HID_ + sc * 8;
  char* la = (char*)lds_a;
  char* lb = (char*)lds_b;
  char* la_w = la + wave * 2048;
  char* lb_w = lb + wave * 4096;
  int swz = (lm >> 1) & 3;
  int fo = (lq ^ swz) << 4;

  f32x4 acc[4][4];
  for (int i = 0; i < 4; i++) for (int j = 0; j < 4; j++) acc[i][j] = (f32x4)0.0f;

  for (int it = 0; it < HID_ / 32; it++) {
    gld16(gA,               la_w);
    gld16(gA + 16 * HID_,   la_w + 1024);
    gld16(gB,               lb_w);
    gld16(gB + 16 * HID_,   lb_w + 1024);
    gld16(gB + 32 * HID_,   lb_w + 2048);
    gld16(gB + 48 * HID_,   lb_w + 3072);
    gA += 32; gB += 32;
    __syncthreads();
    short8 af[4], bfr[4];
#pragma unroll
    for (int mi = 0; mi < 4; mi++)
      af[mi] = *(const short8*)(la + (mi * 16 + lm) * 64 + fo);
#pragma unroll
    for (int ni = 0; ni < 4; ni++)
      bfr[ni] = *(const short8*)(lb + (wave * 64 + ni * 16 + lm) * 64 + fo);
#pragma unroll
    for (int mi = 0; mi < 4; mi++)
#pragma unroll
      for (int ni = 0; ni < 4; ni++)
        acc[mi][ni] = __builtin_amdgcn_mfma_f32_16x16x32_bf16(af[mi], bfr[ni], acc[mi][ni], 0, 0, 0);
    __syncthreads();
  }
  for (int mi = 0; mi < 4; mi++) {
    for (int r = 0; r < 4; r++) {
      int n = n0 + mi * 16 + lq * 4 + r;
      float bias = bv[n];
      for (int ni = 0; ni < 4; ni++) {
        int m = m0 + wave * 64 + ni * 16 + lm;
        int b = m >> 11;
        int s = m & 2047;
        Vt[((size_t)b * NO_ + n) * S_ + s] = f2bf(acc[mi][ni][r] + bias);
      }
    }
  }
}

// ---------------------------------------------------------------------------
// GEMM 2: out[b,q,n] = sum_k Ab[b,q,k] * Vt[b,n,k]   (inv pre-applied in Ab)
// Tile q=128 x n=64, 2 waves (each 64q x 64n). grid (64 cols, 16 q-tiles),
// heavy q-tiles dispatched first (LPT balancing with 4 blocks/CU).
// ---------------------------------------------------------------------------
__global__ __launch_bounds__(128) void k_attn(
    const ushort_t* __restrict__ Ab, const ushort_t* __restrict__ Vt,
    float* __restrict__ out) {
  __shared__ __align__(16) ushort_t lds_a[128 * 32];  // 8 KB, q-rows
  __shared__ __align__(16) ushort_t lds_b[64 * 32];   // 4 KB, n-rows
  int col = blockIdx.x;                 // 64 columns: (n-tile, b)
  int n0 = (col & 15) * 64;
  int b  = col >> 4;
  int t  = 15 - (int)blockIdx.y;        // q-tile, heavy first
  int q0 = t * 128;
  int tid = threadIdx.x;
  int wave = tid >> 6, lane = tid & 63;
  int lq = lane >> 4, lm = lane & 15;

  int rr = lane >> 2;
  int sc = (lane & 3) ^ ((rr >> 1) & 3);
  const ushort_t* gA = Ab + ((size_t)(b * S_ + q0 + wave * 64 + rr)) * S_ + sc * 8;
  const ushort_t* gB = Vt + ((size_t)(b * NO_ + n0 + wave * 32 + rr)) * S_ + sc * 8;
  char* la = (char*)lds_a;
  char* lb = (char*)lds_b;
  char* la_w = la + wave * 4096;
  char* lb_w = lb + wave * 2048;
  int swz = (lm >> 1) & 3;
  int fo = (lq ^ swz) << 4;

  f32x4 acc[4][4];
  for (int i = 0; i < 4; i++) for (int j = 0; j < 4; j++) acc[i][j] = (f32x4)0.0f;

  const int iters = (q0 >> 5) + 4;   // k in [0, q0+128), BK=32
  for (int it = 0; it < iters; it++) {
    gld16(gA,             la_w);
    gld16(gA + 16 * S_,   la_w + 1024);
    gld16(gA + 32 * S_,   la_w + 2048);
    gld16(gA + 48 * S_,   la_w + 3072);
    gld16(gB,             lb_w);
    gld16(gB + 16 * S_,   lb_w + 1024);
    gA += 32; gB += 32;
    __syncthreads();
    short8 af[4], bfr[4];
#pragma unroll
    for (int mi = 0; mi < 4; mi++)
      af[mi] = *(const short8*)(la + (wave * 64 + mi * 16 + lm) * 64 + fo);
#pragma unroll
    for (int ni = 0; ni < 4; ni++)
      bfr[ni] = *(const short8*)(lb + (ni * 16 + lm) * 64 + fo);
#pragma unroll
    for (int mi = 0; mi < 4; mi++)
#pragma unroll
      for (int ni = 0; ni < 4; ni++)
        acc[mi][ni] = __builtin_amdgcn_mfma_f32_16x16x32_bf16(af[mi], bfr[ni], acc[mi][ni], 0, 0, 0);
    __syncthreads();
  }
  for (int mi = 0; mi < 4; mi++) {
    for (int r = 0; r < 4; r++) {
      int q = q0 + wave * 64 + mi * 16 + lq * 4 + r;
      for (int ni = 0; ni < 4; ni++) {
        int n = n0 + ni * 16 + lm;
        out[((size_t)b * S_ + q) * NO_ + n] = acc[mi][ni][r];
      }
    }
  }
}

// ---------------------------------------------------------------------------
extern "C" void kernel_launch(void* const* d_in, const int* in_sizes, int n_in,
                              void* d_out, int out_size, void* d_ws, size_t ws_size,
                              hipStream_t stream) {
  const float* H  = (const float*)d_in[0];   // [B,S,HID]
  const float* A  = (const float*)d_in[1];   // [B,S,S]
  const float* Wv = (const float*)d_in[3];   // [HID, NO]
  const float* bv = (const float*)d_in[4];   // [NO]
  float* out = (float*)d_out;

  char* ws = (char*)d_ws;
  ushort_t* WvT = (ushort_t*)ws;                                  //  2.0 MB
  ushort_t* Hb  = (ushort_t*)(ws + 2097152);                      // 16.8 MB
  ushort_t* Vt  = (ushort_t*)(ws + 2097152 + 16777216);           // 16.8 MB
  ushort_t* Abf = (ushort_t*)(ws + 2097152 + 2 * 16777216);       // 33.6 MB

  k_twv  <<<dim3(HID_ / 32, NO_ / 32), dim3(32, 8), 0, stream>>>(Wv, WvT);
  k_cvtH <<<(M1_ * HID_) / (256 * 4), 256, 0, stream>>>(H, Hb);
  k_prepA<<<M1_ / 4, 256, 0, stream>>>(A, Abf);
  k_vt   <<<dim3(M1_ / 128, NO_ / 64), 128, 0, stream>>>(WvT, Hb, bv, Vt);
  k_attn <<<dim3(64, 16), 128, 0, stream>>>(Abf, Vt, out);
}